// Round 4
// baseline (1007.033 us; speedup 1.0000x reference)
//
#include <hip/hip_runtime.h>
#include <hip/hip_cooperative_groups.h>

namespace cg = cooperative_groups;

typedef unsigned short u16;
typedef unsigned int u32;
typedef __attribute__((ext_vector_type(8))) __bf16 bf16x8;
typedef __attribute__((ext_vector_type(4))) float f32x4;

#define DEVI __device__ __forceinline__
// exp(0.125*d - 16) == exp2(fmaf(d, C1, C2)):
#define C1 0.180336880f    // 0.125 * log2(e)
#define C2 (-23.0831200f)  // -16 * log2(e)

DEVI float bf2f(u16 u) {
    unsigned int v = ((unsigned int)u) << 16;
    return __uint_as_float(v);
}
DEVI u16 f2bf(float f) {
    unsigned int x = __float_as_uint(f);
    x += 0x7fffu + ((x >> 16) & 1u);   // RNE
    return (u16)(x >> 16);
}
DEVI u32 pk2(float lo, float hi) {     // pack 2 f32 -> bf16 pair (RNE)
    union { __bf16 b[2]; u32 u; } c;
    c.b[0] = (__bf16)lo; c.b[1] = (__bf16)hi;
    return c.u;
}
DEVI bf16x8 ldb8(const u16* p) {
    union { uint4 u; bf16x8 b; } c;
    c.u = *(const uint4*)p;
    return c.b;
}
DEVI f32x4 mfma32(bf16x8 a, bf16x8 b, f32x4 c) {
    return __builtin_amdgcn_mfma_f32_16x16x32_bf16(a, b, c, 0, 0, 0);
}
DEVI float clamp4(float v) { return fminf(fmaxf(v, -1e4f), 1e4f); }
DEVI float fexp2(float x) { return __builtin_amdgcn_exp2f(x); }  // v_exp_f32
// async global->LDS, 16B/lane, dest = wave-uniform base + lane*16
DEVI void gld16(const u16* g, u16* l) {
    __builtin_amdgcn_global_load_lds(
        (const __attribute__((address_space(1))) void*)g,
        (__attribute__((address_space(3))) void*)l, 16, 0, 0);
}
// device-scope release/acquire around the grid barrier (G16: per-XCD L2s
// are not coherent; fence emits buffer_wbl2/inv at agent scope on gfx950).
DEVI void gsync() {
    __threadfence();
    cg::this_grid().sync();
    __threadfence();
}

// ---------------------------------------------------------------------------
// prep body: bid in [0,2816).  bid<256: weight transpose (uses LDS T);
// 256..2303: x f32->bf16; 2304..2815: memory-token rows of qkv.
// ---------------------------------------------------------------------------
DEVI void prep_body(char* smem, int bid, int tid,
    const float* __restrict__ wq, const float* __restrict__ wkv,
    const float* __restrict__ wo, const float* __restrict__ x,
    const float* __restrict__ mkf, const float* __restrict__ mvf,
    u16* __restrict__ wqkvT, u16* __restrict__ woT, u16* __restrict__ xb,
    u16* __restrict__ qkv)
{
    if (bid < 256) {
        u16 (*T)[68] = (u16(*)[68])smem;
        int j0, k0; const float* W; int ldw; u16* Out;
        if (bid < 192) { int jt = bid % 24, kt = bid / 24;
            j0 = jt * 64; k0 = kt * 64;
            if (j0 < 512) { W = wq + j0;          ldw = 512;  }
            else          { W = wkv + (j0 - 512); ldw = 1024; }
            Out = wqkvT;
        } else { int t = bid - 192;
            j0 = (t >> 3) * 64; k0 = (t & 7) * 64;
            W = wo + j0; ldw = 512; Out = woT;
        }
        const int lr = tid >> 4, lc = tid & 15;
        #pragma unroll
        for (int i = 0; i < 4; ++i) {
            int k = lr + i * 16;
            float4 v = *(const float4*)(W + (size_t)(k0 + k) * ldw + lc * 4);
            u16 p[4] = { f2bf(v.x), f2bf(v.y), f2bf(v.z), f2bf(v.w) };
            *(uint2*)&T[k][lc * 4] = *(uint2*)p;
        }
        __syncthreads();
        #pragma unroll
        for (int i = 0; i < 4; ++i) {
            int j = lr + i * 16;
            u16 p[4];
            #pragma unroll
            for (int c = 0; c < 4; ++c) p[c] = T[lc * 4 + c][j];
            *(uint2*)(Out + (size_t)(j0 + j) * 512 + k0 + lc * 4) = *(uint2*)p;
        }
        __syncthreads();   // T dead before smem reuse
    } else if (bid < 2304) {
        int e = (bid - 256) * 1024 + tid * 4;
        float4 v = *(const float4*)(x + e);
        u16 p[4] = { f2bf(v.x), f2bf(v.y), f2bf(v.z), f2bf(v.w) };
        *(uint2*)(xb + e) = *(uint2*)p;
    } else {
        int e = (bid - 2304) * 256 + tid;      // 0..131071
        int b = e >> 16, rem = e & 65535;
        int row2 = rem >> 10, c = rem & 1023;  // c<512: K cols, else V cols
        float v = 0.f;
        if (row2 < 3) {
            int hh = (c & 511) >> 6, d = c & 63;
            int src = hh * 192 + row2 * 64 + d;          // flat reshape!
            v = (c < 512) ? 8.0f * mkf[src] : 1.7320508f * mvf[src];
        }
        qkv[((size_t)b * 2112 + 2048 + row2) * 1536 + 512 + c] = f2bf(v);
    }
}

// ---------------------------------------------------------------------------
// gemm body — m97 LDS geometry, BK=64 as two 32-col halves, 2x2 wave grid.
// FM (fuse-merge): A-staging = sum of 4 Opart slabs scaled by 1/l(row,head)
// (per k-step the 64-col group is exactly one head) — replicates merge_kernel
// math op-for-op (f32 sum in slab order, *rl, clamp4, RNE->bf16).
// ---------------------------------------------------------------------------
template<int TM, int TN, bool F32OUT, bool FM>
DEVI void gemm_body(char* smem, int mb, int nb,
    const u16* __restrict__ A, int lda, const u16* __restrict__ BT, int ldb,
    void* __restrict__ Cv, int ldc, const float* __restrict__ bias,
    int K, int mpad, const u16* __restrict__ Op, const float* __restrict__ Lp)
{
    constexpr int IL = TM / 32, JL = TN / 32;
    u16* As0 = (u16*)smem;
    u16* As1 = As0 + TM * 32;
    u16* Bs0 = As1 + TM * 32;
    u16* Bs1 = Bs0 + TN * 32;

    const int tid = threadIdx.x;
    const int m0 = mb * TM, n0 = nb * TN;
    const int w = tid >> 6, lane = tid & 63, l15 = lane & 15, quad = lane >> 4;
    const int wr = w >> 1, wc = w & 1;
    const int sr = lane >> 2, sc = (lane & 3) * 8;

    f32x4 acc[IL][JL];
    #pragma unroll
    for (int i = 0; i < IL; ++i)
        #pragma unroll
        for (int j = 0; j < JL; ++j) acc[i][j] = (f32x4){0.f, 0.f, 0.f, 0.f};

    for (int k0 = 0; k0 < K; k0 += 64) {
        __syncthreads();
        if constexpr (!FM) {
            #pragma unroll
            for (int p = 0; p < TM / 64; ++p) {
                int r0 = w * (TM / 4) + p * 16;
                const u16* g = A + (size_t)(m0 + r0 + sr) * lda + k0 + sc;
                gld16(g,      &As0[r0 * 32]);
                gld16(g + 32, &As1[r0 * 32]);
            }
        } else {
            const int h = k0 >> 6;                    // head of this k-group
            #pragma unroll
            for (int p = 0; p < TM / 64; ++p) {
                int r0 = w * (TM / 4) + p * 16;
                int row = m0 + r0 + sr;
                float l = Lp[(size_t)row * 8 + h]
                        + Lp[((size_t)4096  + row) * 8 + h]
                        + Lp[((size_t)8192  + row) * 8 + h]
                        + Lp[((size_t)12288 + row) * 8 + h];
                float rl = 1.0f / fmaxf(l, 1e-30f);
                const u16* g = Op + (size_t)row * 512 + k0 + sc;
                #pragma unroll
                for (int hf = 0; hf < 2; ++hf) {
                    const u16* gh = g + hf * 32;
                    float a8[8] = {0.f,0.f,0.f,0.f,0.f,0.f,0.f,0.f};
                    #pragma unroll
                    for (int sl = 0; sl < 4; ++sl) {
                        uint4 pv = *(const uint4*)(gh + (size_t)sl * 2097152);
                        a8[0] += bf2f((u16)(pv.x & 0xffff)); a8[1] += bf2f((u16)(pv.x >> 16));
                        a8[2] += bf2f((u16)(pv.y & 0xffff)); a8[3] += bf2f((u16)(pv.y >> 16));
                        a8[4] += bf2f((u16)(pv.z & 0xffff)); a8[5] += bf2f((u16)(pv.z >> 16));
                        a8[6] += bf2f((u16)(pv.w & 0xffff)); a8[7] += bf2f((u16)(pv.w >> 16));
                    }
                    u16 ob[8];
                    #pragma unroll
                    for (int i = 0; i < 8; ++i) ob[i] = f2bf(clamp4(a8[i] * rl));
                    u16* dst = (hf ? As1 : As0) + (r0 + sr) * 32 + sc;  // linear lane*16B
                    *(uint4*)dst = *(uint4*)ob;
                }
            }
        }
        #pragma unroll
        for (int p = 0; p < TN / 64; ++p) {
            int r0 = w * (TN / 4) + p * 16;
            const u16* g = BT + (size_t)(n0 + r0 + sr) * ldb + k0 + sc;
            gld16(g,      &Bs0[r0 * 32]);
            gld16(g + 32, &Bs1[r0 * 32]);
        }
        __syncthreads();

        #pragma unroll
        for (int ks = 0; ks < 2; ++ks) {
            const u16* Asel = ks ? As1 : As0;
            const u16* Bsel = ks ? Bs1 : Bs0;
            bf16x8 af[IL], bf[JL];
            #pragma unroll
            for (int i = 0; i < IL; ++i)
                af[i] = ldb8(&Asel[(wr * (TM / 2) + 16 * i + l15) * 32 + quad * 8]);
            #pragma unroll
            for (int j = 0; j < JL; ++j)
                bf[j] = ldb8(&Bsel[(wc * (TN / 2) + 16 * j + l15) * 32 + quad * 8]);
            #pragma unroll
            for (int i = 0; i < IL; ++i)
                #pragma unroll
                for (int j = 0; j < JL; ++j)
                    acc[i][j] = mfma32(af[i], bf[j], acc[i][j]);
        }
    }

    #pragma unroll
    for (int j = 0; j < JL; ++j) {
        int col = n0 + wc * (TN / 2) + 16 * j + l15;
        float bv = bias ? bias[col] : 0.f;
        #pragma unroll
        for (int i = 0; i < IL; ++i) {
            #pragma unroll
            for (int r = 0; r < 4; ++r) {
                int row = m0 + wr * (TM / 2) + 16 * i + quad * 4 + r;
                int orow = row + ((row >> 11) * mpad);
                float vr = clamp4(acc[i][j][r] + bv);
                if (F32OUT) ((float*)Cv)[(size_t)orow * ldc + col] = vr;
                else        ((u16*)Cv)[(size_t)orow * ldc + col] = f2bf(vr);
            }
        }
    }
}

// ---------------------------------------------------------------------------
// flash attention body.  q-tile 128 (2 subtiles/wave), S^T orientation,
// fixed-max softmax (exp2), l via MFMA against a register ones-fragment.
// split-K x4: vb&63 = qt*4 + s; h=(vb>>6)&7; b=vb>>9.
// LDS: Ks 9K + Vt 9K + Ps 18K = 36,864 B.
// (r2 counters: MfmaUtil 30, VALUBusy 52, 3.8e6 conflict-cyc/rep — VALU-bound)
// ---------------------------------------------------------------------------
DEVI void attn_body(char* smem, int vb,
    const u16* __restrict__ qkv, u16* __restrict__ Opart,
    float* __restrict__ Lpart)
{
    u16 (*Ks)[72] = (u16(*)[72])smem;
    u16 (*Vt)[72] = (u16(*)[72])(smem + 9216);
    u16 (*Ps)[72] = (u16(*)[72])(smem + 18432);

    const int tid = threadIdx.x;
    const int bx = vb & 63;
    const int qt = bx >> 2, s = bx & 3;
    const int h = (vb >> 6) & 7, b = vb >> 9;
    const int w = tid >> 6, lane = tid & 63, l15 = lane & 15, quad = lane >> 4;
    const size_t bq = (size_t)b * 2112;
    const int rq = qt * 128;
    const int ro = b * 2048 + qt * 128;

    // register ones-fragment for the l-column MFMA (bf16 1.0 = 0x3F80)
    union { u32 u[4]; bf16x8 b8; } onesu;
    #pragma unroll
    for (int i = 0; i < 4; ++i) onesu.u[i] = 0x3F803F80u;
    const bf16x8 onesf = onesu.b8;

    // ---- stage Q 128x64 into Ps (raw; scale folded into exp2) ----
    {
        int row = tid >> 1, cg = (tid & 1) * 32;
        const u16* src = qkv + (bq + rq + row) * 1536 + h * 64 + cg;
        *(uint4*)&Ps[row][cg]      = *(const uint4*)src;
        *(uint4*)&Ps[row][cg + 8]  = *(const uint4*)(src + 8);
        *(uint4*)&Ps[row][cg + 16] = *(const uint4*)(src + 16);
        *(uint4*)&Ps[row][cg + 24] = *(const uint4*)(src + 24);
    }
    __syncthreads();
    bf16x8 qf[2][2];
    #pragma unroll
    for (int sub = 0; sub < 2; ++sub) {
        qf[sub][0] = ldb8(&Ps[64 * sub + 16 * w + l15][quad * 8]);
        qf[sub][1] = ldb8(&Ps[64 * sub + 16 * w + l15][32 + quad * 8]);
    }

    f32x4 Od[2][4], Ol[2];
    #pragma unroll
    for (int sub = 0; sub < 2; ++sub) {
        #pragma unroll
        for (int t = 0; t < 4; ++t) Od[sub][t] = (f32x4){0.f, 0.f, 0.f, 0.f};
        Ol[sub] = (f32x4){0.f, 0.f, 0.f, 0.f};
    }

    const int krow = tid >> 2, kcg = (tid & 3) * 16;
    const int vkp = (tid & 31) * 2, vdg = ((tid >> 5) & 7) * 8;

    const int kt0 = s ? 8 * s + 1 : 0;        // {0,9,17,25}
    const int kt1 = 8 * s + 9;                // {9,17,25,33}
    for (int kt = kt0; kt < kt1; ++kt) {
        // ---- global loads early (K tile + V tile) ----
        const u16* ksrc = qkv + (bq + kt * 64 + krow) * 1536 + 512 + h * 64 + kcg;
        uint4 k0 = *(const uint4*)ksrc, k1 = *(const uint4*)(ksrc + 8);
        const u16* vsrc = qkv + (bq + kt * 64 + vkp) * 1536 + 1024 + h * 64 + vdg;
        uint4 v0 = *(const uint4*)vsrc, v1 = *(const uint4*)(vsrc + 1536);
        __syncthreads();   // prior iter's frag reads done
        *(uint4*)&Ks[krow][kcg]     = k0;
        *(uint4*)&Ks[krow][kcg + 8] = k1;
        {
            u32 a0[4] = {v0.x, v0.y, v0.z, v0.w};
            u32 a1[4] = {v1.x, v1.y, v1.z, v1.w};
            #pragma unroll
            for (int i = 0; i < 4; ++i) {
                u32 lo = __builtin_amdgcn_perm(a1[i], a0[i], 0x05040100u);
                u32 hi = __builtin_amdgcn_perm(a1[i], a0[i], 0x07060302u);
                *(u32*)&Vt[vdg + 2 * i][vkp]     = lo;
                *(u32*)&Vt[vdg + 2 * i + 1][vkp] = hi;
            }
        }
        __syncthreads();

        // ---- S^T = K @ Q^T, 2 subtiles; each kf read feeds 2 MFMA ----
        f32x4 d[2][4];
        #pragma unroll
        for (int sub = 0; sub < 2; ++sub)
            #pragma unroll
            for (int t = 0; t < 4; ++t) d[sub][t] = (f32x4){0.f, 0.f, 0.f, 0.f};
        #pragma unroll
        for (int ks = 0; ks < 2; ++ks) {
            #pragma unroll
            for (int t = 0; t < 4; ++t) {
                bf16x8 kf = ldb8(&Ks[16 * t + l15][ks * 32 + quad * 8]);
                d[0][t] = mfma32(kf, qf[0][ks], d[0][t]);
                d[1][t] = mfma32(kf, qf[1][ks], d[1][t]);
            }
        }
        if (kt == 32) {   // keys 2048..2050 valid -> local key 16t+4quad+r < 3
            #pragma unroll
            for (int sub = 0; sub < 2; ++sub) {
                #pragma unroll
                for (int t = 1; t < 4; ++t)
                    d[sub][t] = (f32x4){-1e9f, -1e9f, -1e9f, -1e9f};
                #pragma unroll
                for (int r = 0; r < 4; ++r)
                    if (!(quad == 0 && r < 3)) d[sub][0][r] = -1e9f;
            }
        }

        // ---- p = exp2(fmaf(d,C1,C2)); b64 stores (wave-private rows) ----
        #pragma unroll
        for (int sub = 0; sub < 2; ++sub)
            #pragma unroll
            for (int t = 0; t < 4; ++t) {
                uint2 pv = { pk2(fexp2(fmaf(d[sub][t][0], C1, C2)),
                                 fexp2(fmaf(d[sub][t][1], C1, C2))),
                             pk2(fexp2(fmaf(d[sub][t][2], C1, C2)),
                                 fexp2(fmaf(d[sub][t][3], C1, C2))) };
                *(uint2*)&Ps[64 * sub + 16 * w + l15][16 * t + 4 * quad] = pv;
            }
        // ---- O += P @ V; l += P @ 1 (register fragment, no LDS read) ----
        #pragma unroll
        for (int ks = 0; ks < 2; ++ks) {
            bf16x8 af0 = ldb8(&Ps[16 * w + l15][ks * 32 + quad * 8]);
            bf16x8 af1 = ldb8(&Ps[64 + 16 * w + l15][ks * 32 + quad * 8]);
            #pragma unroll
            for (int dt = 0; dt < 4; ++dt) {
                bf16x8 vf = ldb8(&Vt[16 * dt + l15][ks * 32 + quad * 8]);
                Od[0][dt] = mfma32(af0, vf, Od[0][dt]);
                Od[1][dt] = mfma32(af1, vf, Od[1][dt]);
            }
            Ol[0] = mfma32(af0, onesf, Ol[0]);
            Ol[1] = mfma32(af1, onesf, Ol[1]);
        }
    }

    // ---- epilogue ----
    u16* Ob = Opart + (size_t)s * 4096 * 512;
    #pragma unroll
    for (int sub = 0; sub < 2; ++sub) {
        #pragma unroll
        for (int r = 0; r < 4; ++r) {
            int row = ro + 64 * sub + 16 * w + quad * 4 + r;
            #pragma unroll
            for (int dt = 0; dt < 4; ++dt) {
                int col = h * 64 + 16 * dt + l15;
                Ob[(size_t)row * 512 + col] = f2bf(Od[sub][dt][r]);
            }
            if (l15 == 0)
                Lpart[((size_t)s * 4096 + row) * 8 + h] = Ol[sub][r];
        }
    }
}

// ---------------------------------------------------------------------------
// MEGA-KERNEL: all phases in one cooperative dispatch (kills ~4 launch gaps).
// grid=1024, block=256, LDS=36,864 -> exactly 4 blocks/CU co-resident.
// ---------------------------------------------------------------------------
__global__ __launch_bounds__(256, 4) void fused(
    const float* __restrict__ wq, const float* __restrict__ wkv,
    const float* __restrict__ wo, const float* __restrict__ x,
    const float* __restrict__ mkf, const float* __restrict__ mvf,
    const float* __restrict__ bo,
    u16* __restrict__ wqkvT, u16* __restrict__ woT, u16* __restrict__ xb,
    u16* __restrict__ qkv, u16* __restrict__ Opart, float* __restrict__ Lpart,
    float* __restrict__ out)
{
    __shared__ alignas(16) char smem[36864];
    const int tid = threadIdx.x;
    const int gbid = blockIdx.x;

    // phase 0: prep (2816 virtual blocks, grid-stride over 1024)
    for (int bid = gbid; bid < 2816; bid += 1024)
        prep_body(smem, bid, tid, wq, wkv, wo, x, mkf, mvf, wqkvT, woT, xb, qkv);
    gsync();

    // phase 1: QKV gemm (768 tiles; blocks 768..1023 idle)
    if (gbid < 768)
        gemm_body<128, 64, false, false>(smem, gbid & 31, gbid >> 5,
            xb, 512, wqkvT, 512, qkv, 1536, nullptr, 512, 64, nullptr, nullptr);
    gsync();

    // phase 2: flash attention (all 1024 blocks)
    attn_body(smem, gbid, qkv, Opart, Lpart);
    gsync();

    // phase 3: O-projection gemm with fused merge (512 tiles)
    if (gbid < 512)
        gemm_body<64, 64, true, true>(smem, gbid & 63, gbid >> 6,
            nullptr, 512, woT, 512, out, 512, bo, 512, 0, Opart, Lpart);
}

// ---------------------------------------------------------------------------
// Fallback path (5 separate dispatches) — used if cooperative launch fails.
// ---------------------------------------------------------------------------
__global__ __launch_bounds__(256) void prep(
    const float* __restrict__ wq, const float* __restrict__ wkv,
    const float* __restrict__ wo, const float* __restrict__ x,
    const float* __restrict__ mkf, const float* __restrict__ mvf,
    u16* __restrict__ wqkvT, u16* __restrict__ woT, u16* __restrict__ xb,
    u16* __restrict__ qkv)
{
    __shared__ alignas(16) char smem[64 * 68 * 2];
    prep_body(smem, blockIdx.x, threadIdx.x, wq, wkv, wo, x, mkf, mvf,
              wqkvT, woT, xb, qkv);
}

template<int TM, int TN, bool F32OUT>
__global__ __launch_bounds__(256) void gemmK(
    const u16* __restrict__ A, int lda, const u16* __restrict__ BT, int ldb,
    void* __restrict__ Cv, int ldc, const float* __restrict__ bias,
    int K, int mpad)
{
    __shared__ alignas(16) char smem[(2 * TM * 32 + 2 * TN * 32) * 2];
    gemm_body<TM, TN, F32OUT, false>(smem, blockIdx.x, blockIdx.y,
        A, lda, BT, ldb, Cv, ldc, bias, K, mpad, nullptr, nullptr);
}

__global__ __launch_bounds__(256, 4) void attn_kernel(
    const u16* __restrict__ qkv, u16* __restrict__ Opart,
    float* __restrict__ Lpart)
{
    __shared__ alignas(16) char smem[36864];
    attn_body(smem, (int)(blockIdx.x + (blockIdx.y << 6) + (blockIdx.z << 9)),
              qkv, Opart, Lpart);
}

__global__ __launch_bounds__(256) void merge_kernel(
    const u16* __restrict__ Opart, const float* __restrict__ Lpart,
    u16* __restrict__ outp)
{
    int e = (blockIdx.x * 256 + threadIdx.x) * 4;
    int row = e >> 9, h = (e & 511) >> 6;
    float ax = 0.f, ay = 0.f, az = 0.f, aw = 0.f, l = 0.f;
    #pragma unroll
    for (int s = 0; s < 4; ++s) {
        uint2 pv = *(const uint2*)(Opart + (size_t)s * 4096 * 512 + e);
        ax += bf2f((u16)(pv.x & 0xffff)); ay += bf2f((u16)(pv.x >> 16));
        az += bf2f((u16)(pv.y & 0xffff)); aw += bf2f((u16)(pv.y >> 16));
        l += Lpart[((size_t)s * 4096 + row) * 8 + h];
    }
    float rl = 1.0f / fmaxf(l, 1e-30f);
    u16 p[4] = { f2bf(clamp4(ax * rl)), f2bf(clamp4(ay * rl)),
                 f2bf(clamp4(az * rl)), f2bf(clamp4(aw * rl)) };
    *(uint2*)(outp + e) = *(uint2*)p;
}

// ---------------------------------------------------------------------------
extern "C" void kernel_launch(void* const* d_in, const int* in_sizes, int n_in,
                              void* d_out, int out_size, void* d_ws, size_t ws_size,
                              hipStream_t stream)
{
    (void)in_sizes; (void)n_in; (void)out_size; (void)ws_size;
    const float* x   = (const float*)d_in[0];
    const float* wq  = (const float*)d_in[1];
    const float* wkv = (const float*)d_in[2];
    const float* wo  = (const float*)d_in[3];
    const float* bo  = (const float*)d_in[4];
    const float* mk  = (const float*)d_in[5];
    const float* mv  = (const float*)d_in[6];
    float* out = (float*)d_out;

    // non-aliased workspace layout (fused kernel: no address reuse across
    // phases -> no stale-L2 lines; ~41 MB of the 268 MB ws)
    u16* qkv    = (u16*)d_ws;                 // 6,488,064 u16
    u16* woT    = qkv + 6488064;              //   262,144
    u16* wqkvT  = woT + 262144;               //   786,432
    u16* xb     = wqkvT + 786432;             // 2,097,152
    u16* Opart  = xb + 2097152;               // 8,388,608 (4 slabs)
    float* Lpart = (float*)(Opart + 8388608); //   131,072 f32
    u16* outp   = (u16*)(Lpart + 131072);     // 2,097,152 (fallback only)

    void* kargs[] = {
        (void*)&wq, (void*)&wkv, (void*)&wo, (void*)&x, (void*)&mk, (void*)&mv,
        (void*)&bo, (void*)&wqkvT, (void*)&woT, (void*)&xb, (void*)&qkv,
        (void*)&Opart, (void*)&Lpart, (void*)&out
    };
    hipError_t err = hipLaunchCooperativeKernel(
        (const void*)fused, dim3(1024), dim3(256), kargs, 0, stream);
    if (err != hipSuccess) {
        (void)hipGetLastError();   // clear; take the proven 5-kernel path
        prep<<<2816, 256, 0, stream>>>(wq, wkv, wo, x, mk, mv, wqkvT, woT, xb, qkv);
        gemmK<128, 64, false><<<dim3(32, 24), 256, 0, stream>>>(
            xb, 512, wqkvT, 512, qkv, 1536, nullptr, 512, 64);
        attn_kernel<<<dim3(64, 8, 2), 256, 0, stream>>>(qkv, Opart, Lpart);
        merge_kernel<<<2048, 256, 0, stream>>>(Opart, Lpart, outp);
        gemmK<64, 64, true><<<dim3(64, 8), 256, 0, stream>>>(
            outp, 512, woT, 512, out, 512, bo, 512, 0);
    }
}

// Round 5
// 130.958 us; speedup vs baseline: 7.6897x; 7.6897x over previous
//
#include <hip/hip_runtime.h>

typedef unsigned short u16;
typedef unsigned int u32;
typedef __attribute__((ext_vector_type(8))) __bf16 bf16x8;
typedef __attribute__((ext_vector_type(4))) float f32x4;

#define DEVI __device__ __forceinline__
// exp(0.125*d - 16) == exp2(fmaf(d, C1, C2)):
#define C1 0.180336880f    // 0.125 * log2(e)
#define C2 (-23.0831200f)  // -16 * log2(e)

DEVI float bf2f(u16 u) {
    unsigned int v = ((unsigned int)u) << 16;
    return __uint_as_float(v);
}
DEVI u16 f2bf(float f) {
    unsigned int x = __float_as_uint(f);
    x += 0x7fffu + ((x >> 16) & 1u);   // RNE
    return (u16)(x >> 16);
}
DEVI u32 pk2(float lo, float hi) {     // pack 2 f32 -> bf16 pair (RNE)
    union { __bf16 b[2]; u32 u; } c;
    c.b[0] = (__bf16)lo; c.b[1] = (__bf16)hi;
    return c.u;
}
DEVI bf16x8 ldb8(const u16* p) {
    union { uint4 u; bf16x8 b; } c;
    c.u = *(const uint4*)p;
    return c.b;
}
DEVI f32x4 mfma32(bf16x8 a, bf16x8 b, f32x4 c) {
    return __builtin_amdgcn_mfma_f32_16x16x32_bf16(a, b, c, 0, 0, 0);
}
DEVI float clamp4(float v) { return fminf(fmaxf(v, -1e4f), 1e4f); }
DEVI float fexp2(float x) { return __builtin_amdgcn_exp2f(x); }  // v_exp_f32
// async global->LDS, 16B/lane, dest = wave-uniform base + lane*16
DEVI void gld16(const u16* g, u16* l) {
    __builtin_amdgcn_global_load_lds(
        (const __attribute__((address_space(1))) void*)g,
        (__attribute__((address_space(3))) void*)l, 16, 0, 0);
}

// ---------------------------------------------------------------------------
// Kernel 1: prep (unchanged, proven).
// ---------------------------------------------------------------------------
__global__ __launch_bounds__(256) void prep(
    const float* __restrict__ wq, const float* __restrict__ wkv,
    const float* __restrict__ wo, const float* __restrict__ x,
    const float* __restrict__ mkf, const float* __restrict__ mvf,
    u16* __restrict__ wqkvT, u16* __restrict__ woT, u16* __restrict__ xb,
    u16* __restrict__ qkv)
{
    const int bid = blockIdx.x, tid = threadIdx.x;
    if (bid < 256) {
        __shared__ u16 T[64][68];
        int j0, k0; const float* W; int ldw; u16* Out;
        if (bid < 192) { int jt = bid % 24, kt = bid / 24;
            j0 = jt * 64; k0 = kt * 64;
            if (j0 < 512) { W = wq + j0;          ldw = 512;  }
            else          { W = wkv + (j0 - 512); ldw = 1024; }
            Out = wqkvT;
        } else { int t = bid - 192;
            j0 = (t >> 3) * 64; k0 = (t & 7) * 64;
            W = wo + j0; ldw = 512; Out = woT;
        }
        const int lr = tid >> 4, lc = tid & 15;
        #pragma unroll
        for (int i = 0; i < 4; ++i) {
            int k = lr + i * 16;
            float4 v = *(const float4*)(W + (size_t)(k0 + k) * ldw + lc * 4);
            u16 p[4] = { f2bf(v.x), f2bf(v.y), f2bf(v.z), f2bf(v.w) };
            *(uint2*)&T[k][lc * 4] = *(uint2*)p;
        }
        __syncthreads();
        #pragma unroll
        for (int i = 0; i < 4; ++i) {
            int j = lr + i * 16;
            u16 p[4];
            #pragma unroll
            for (int c = 0; c < 4; ++c) p[c] = T[lc * 4 + c][j];
            *(uint2*)(Out + (size_t)(j0 + j) * 512 + k0 + lc * 4) = *(uint2*)p;
        }
    } else if (bid < 2304) {
        int e = (bid - 256) * 1024 + tid * 4;
        float4 v = *(const float4*)(x + e);
        u16 p[4] = { f2bf(v.x), f2bf(v.y), f2bf(v.z), f2bf(v.w) };
        *(uint2*)(xb + e) = *(uint2*)p;
    } else {
        int e = (bid - 2304) * 256 + tid;      // 0..131071
        int b = e >> 16, rem = e & 65535;
        int row2 = rem >> 10, c = rem & 1023;  // c<512: K cols, else V cols
        float v = 0.f;
        if (row2 < 3) {
            int hh = (c & 511) >> 6, d = c & 63;
            int src = hh * 192 + row2 * 64 + d;          // flat reshape!
            v = (c < 512) ? 8.0f * mkf[src] : 1.7320508f * mvf[src];
        }
        qkv[((size_t)b * 2112 + 2048 + row2) * 1536 + 512 + c] = f2bf(v);
    }
}

// ---------------------------------------------------------------------------
// Kernel 2/4: gemmK — m97 LDS geometry, BK=64 as two 32-col halves, 2x2 waves.
// FM (fuse-merge, PROVEN bit-identical in r4): A-staging = sum of 4 Opart
// slabs scaled by 1/l(row,head); per k-step the 64-col group is one head.
// Replicates merge_kernel math op-for-op (f32 sum in slab order, *rl,
// clamp4, RNE->bf16) before the MFMA consumes it.
// gemm1: <128,64,false,false> grid(32,24).  gemm2: <64,64,true,true> grid(64,8).
// ---------------------------------------------------------------------------
template<int TM, int TN, bool F32OUT, bool FM>
__global__ __launch_bounds__(256) void gemmK(
    const u16* __restrict__ A, int lda,
    const u16* __restrict__ BT, int ldb,
    void* __restrict__ Cv, int ldc,
    const float* __restrict__ bias, int K, int mpad,
    const u16* __restrict__ Op, const float* __restrict__ Lp)
{
    constexpr int IL = TM / 32, JL = TN / 32;
    __shared__ u16 As0[TM * 32], As1[TM * 32];
    __shared__ u16 Bs0[TN * 32], Bs1[TN * 32];

    const int tid = threadIdx.x;
    const int m0 = blockIdx.x * TM, n0 = blockIdx.y * TN;
    const int w = tid >> 6, lane = tid & 63, l15 = lane & 15, quad = lane >> 4;
    const int wr = w >> 1, wc = w & 1;
    const int sr = lane >> 2, sc = (lane & 3) * 8;

    f32x4 acc[IL][JL];
    #pragma unroll
    for (int i = 0; i < IL; ++i)
        #pragma unroll
        for (int j = 0; j < JL; ++j) acc[i][j] = (f32x4){0.f, 0.f, 0.f, 0.f};

    for (int k0 = 0; k0 < K; k0 += 64) {
        __syncthreads();
        if constexpr (!FM) {
            #pragma unroll
            for (int p = 0; p < TM / 64; ++p) {
                int r0 = w * (TM / 4) + p * 16;
                const u16* g = A + (size_t)(m0 + r0 + sr) * lda + k0 + sc;
                gld16(g,      &As0[r0 * 32]);
                gld16(g + 32, &As1[r0 * 32]);
            }
        } else {
            const int h = k0 >> 6;                    // head of this k-group
            #pragma unroll
            for (int p = 0; p < TM / 64; ++p) {
                int r0 = w * (TM / 4) + p * 16;
                int row = m0 + r0 + sr;
                float l = Lp[(size_t)row * 8 + h]
                        + Lp[((size_t)4096  + row) * 8 + h]
                        + Lp[((size_t)8192  + row) * 8 + h]
                        + Lp[((size_t)12288 + row) * 8 + h];
                float rl = 1.0f / fmaxf(l, 1e-30f);
                const u16* g = Op + (size_t)row * 512 + k0 + sc;
                #pragma unroll
                for (int hf = 0; hf < 2; ++hf) {
                    const u16* gh = g + hf * 32;
                    float a8[8] = {0.f,0.f,0.f,0.f,0.f,0.f,0.f,0.f};
                    #pragma unroll
                    for (int sl = 0; sl < 4; ++sl) {
                        uint4 pv = *(const uint4*)(gh + (size_t)sl * 2097152);
                        a8[0] += bf2f((u16)(pv.x & 0xffff)); a8[1] += bf2f((u16)(pv.x >> 16));
                        a8[2] += bf2f((u16)(pv.y & 0xffff)); a8[3] += bf2f((u16)(pv.y >> 16));
                        a8[4] += bf2f((u16)(pv.z & 0xffff)); a8[5] += bf2f((u16)(pv.z >> 16));
                        a8[6] += bf2f((u16)(pv.w & 0xffff)); a8[7] += bf2f((u16)(pv.w >> 16));
                    }
                    u16 ob[8];
                    #pragma unroll
                    for (int i = 0; i < 8; ++i) ob[i] = f2bf(clamp4(a8[i] * rl));
                    u16* dst = (hf ? As1 : As0) + (r0 + sr) * 32 + sc;
                    *(uint4*)dst = *(uint4*)ob;
                }
            }
        }
        #pragma unroll
        for (int p = 0; p < TN / 64; ++p) {
            int r0 = w * (TN / 4) + p * 16;
            const u16* g = BT + (size_t)(n0 + r0 + sr) * ldb + k0 + sc;
            gld16(g,      &Bs0[r0 * 32]);
            gld16(g + 32, &Bs1[r0 * 32]);
        }
        __syncthreads();

        #pragma unroll
        for (int ks = 0; ks < 2; ++ks) {
            const u16* Asel = ks ? As1 : As0;
            const u16* Bsel = ks ? Bs1 : Bs0;
            bf16x8 af[IL], bf[JL];
            #pragma unroll
            for (int i = 0; i < IL; ++i)
                af[i] = ldb8(&Asel[(wr * (TM / 2) + 16 * i + l15) * 32 + quad * 8]);
            #pragma unroll
            for (int j = 0; j < JL; ++j)
                bf[j] = ldb8(&Bsel[(wc * (TN / 2) + 16 * j + l15) * 32 + quad * 8]);
            #pragma unroll
            for (int i = 0; i < IL; ++i)
                #pragma unroll
                for (int j = 0; j < JL; ++j)
                    acc[i][j] = mfma32(af[i], bf[j], acc[i][j]);
        }
    }

    #pragma unroll
    for (int j = 0; j < JL; ++j) {
        int col = n0 + wc * (TN / 2) + 16 * j + l15;
        float bv = bias ? bias[col] : 0.f;
        #pragma unroll
        for (int i = 0; i < IL; ++i) {
            #pragma unroll
            for (int r = 0; r < 4; ++r) {
                int row = m0 + wr * (TM / 2) + 16 * i + quad * 4 + r;
                int orow = row + ((row >> 11) * mpad);
                float vr = clamp4(acc[i][j][r] + bv);
                if (F32OUT) ((float*)Cv)[(size_t)orow * ldc + col] = vr;
                else        ((u16*)Cv)[(size_t)orow * ldc + col] = f2bf(vr);
            }
        }
    }
}

// ---------------------------------------------------------------------------
// Kernel 3: flash attention (unchanged, proven).  q-tile 128, S^T orientation,
// fixed-max softmax (exp2), l via MFMA against a register ones-fragment.
// split-K x4: blockIdx.x = qt*4 + s.  LDS 36,864 B -> 4 blocks/CU.
// (r2 counters: MfmaUtil 30, VALUBusy 52 -> VALU-bound; conflicts all 2-way
//  by static analysis = free per m136; measured counter likely inter-wave.)
// ---------------------------------------------------------------------------
__global__ __launch_bounds__(256, 4) void attn_kernel(
    const u16* __restrict__ qkv, u16* __restrict__ Opart,
    float* __restrict__ Lpart)
{
    __shared__ alignas(16) u16 Ks[64][72];
    __shared__ alignas(16) u16 Vt[64][72];
    __shared__ alignas(16) u16 Ps[128][72];   // Q at start, then P (2 subtiles)

    const int tid = threadIdx.x;
    const int bx = blockIdx.x;
    const int qt = bx >> 2, s = bx & 3;
    const int h = blockIdx.y, b = blockIdx.z;
    const int w = tid >> 6, lane = tid & 63, l15 = lane & 15, quad = lane >> 4;
    const size_t bq = (size_t)b * 2112;
    const int rq = qt * 128;
    const int ro = b * 2048 + qt * 128;

    // register ones-fragment for the l-column MFMA (bf16 1.0 = 0x3F80)
    union { u32 u[4]; bf16x8 b8; } onesu;
    #pragma unroll
    for (int i = 0; i < 4; ++i) onesu.u[i] = 0x3F803F80u;
    const bf16x8 onesf = onesu.b8;

    // ---- stage Q 128x64 into Ps (raw; scale folded into exp2) ----
    {
        int row = tid >> 1, cg = (tid & 1) * 32;
        const u16* src = qkv + (bq + rq + row) * 1536 + h * 64 + cg;
        *(uint4*)&Ps[row][cg]      = *(const uint4*)src;
        *(uint4*)&Ps[row][cg + 8]  = *(const uint4*)(src + 8);
        *(uint4*)&Ps[row][cg + 16] = *(const uint4*)(src + 16);
        *(uint4*)&Ps[row][cg + 24] = *(const uint4*)(src + 24);
    }
    __syncthreads();
    bf16x8 qf[2][2];
    #pragma unroll
    for (int sub = 0; sub < 2; ++sub) {
        qf[sub][0] = ldb8(&Ps[64 * sub + 16 * w + l15][quad * 8]);
        qf[sub][1] = ldb8(&Ps[64 * sub + 16 * w + l15][32 + quad * 8]);
    }

    f32x4 Od[2][4], Ol[2];
    #pragma unroll
    for (int sub = 0; sub < 2; ++sub) {
        #pragma unroll
        for (int t = 0; t < 4; ++t) Od[sub][t] = (f32x4){0.f, 0.f, 0.f, 0.f};
        Ol[sub] = (f32x4){0.f, 0.f, 0.f, 0.f};
    }

    const int krow = tid >> 2, kcg = (tid & 3) * 16;
    const int vkp = (tid & 31) * 2, vdg = ((tid >> 5) & 7) * 8;

    const int kt0 = s ? 8 * s + 1 : 0;        // {0,9,17,25}
    const int kt1 = 8 * s + 9;                // {9,17,25,33}
    for (int kt = kt0; kt < kt1; ++kt) {
        // ---- global loads early (K tile + V tile) ----
        const u16* ksrc = qkv + (bq + kt * 64 + krow) * 1536 + 512 + h * 64 + kcg;
        uint4 k0 = *(const uint4*)ksrc, k1 = *(const uint4*)(ksrc + 8);
        const u16* vsrc = qkv + (bq + kt * 64 + vkp) * 1536 + 1024 + h * 64 + vdg;
        uint4 v0 = *(const uint4*)vsrc, v1 = *(const uint4*)(vsrc + 1536);
        __syncthreads();   // prior iter's frag reads done
        *(uint4*)&Ks[krow][kcg]     = k0;
        *(uint4*)&Ks[krow][kcg + 8] = k1;
        {
            u32 a0[4] = {v0.x, v0.y, v0.z, v0.w};
            u32 a1[4] = {v1.x, v1.y, v1.z, v1.w};
            #pragma unroll
            for (int i = 0; i < 4; ++i) {
                u32 lo = __builtin_amdgcn_perm(a1[i], a0[i], 0x05040100u);
                u32 hi = __builtin_amdgcn_perm(a1[i], a0[i], 0x07060302u);
                *(u32*)&Vt[vdg + 2 * i][vkp]     = lo;
                *(u32*)&Vt[vdg + 2 * i + 1][vkp] = hi;
            }
        }
        __syncthreads();

        // ---- S^T = K @ Q^T, 2 subtiles; each kf read feeds 2 MFMA ----
        f32x4 d[2][4];
        #pragma unroll
        for (int sub = 0; sub < 2; ++sub)
            #pragma unroll
            for (int t = 0; t < 4; ++t) d[sub][t] = (f32x4){0.f, 0.f, 0.f, 0.f};
        #pragma unroll
        for (int ks = 0; ks < 2; ++ks) {
            #pragma unroll
            for (int t = 0; t < 4; ++t) {
                bf16x8 kf = ldb8(&Ks[16 * t + l15][ks * 32 + quad * 8]);
                d[0][t] = mfma32(kf, qf[0][ks], d[0][t]);
                d[1][t] = mfma32(kf, qf[1][ks], d[1][t]);
            }
        }
        if (kt == 32) {   // keys 2048..2050 valid -> local key 16t+4quad+r < 3
            #pragma unroll
            for (int sub = 0; sub < 2; ++sub) {
                #pragma unroll
                for (int t = 1; t < 4; ++t)
                    d[sub][t] = (f32x4){-1e9f, -1e9f, -1e9f, -1e9f};
                #pragma unroll
                for (int r = 0; r < 4; ++r)
                    if (!(quad == 0 && r < 3)) d[sub][0][r] = -1e9f;
            }
        }

        // ---- p = exp2(fmaf(d,C1,C2)); b64 stores (wave-private rows) ----
        #pragma unroll
        for (int sub = 0; sub < 2; ++sub)
            #pragma unroll
            for (int t = 0; t < 4; ++t) {
                uint2 pv = { pk2(fexp2(fmaf(d[sub][t][0], C1, C2)),
                                 fexp2(fmaf(d[sub][t][1], C1, C2))),
                             pk2(fexp2(fmaf(d[sub][t][2], C1, C2)),
                                 fexp2(fmaf(d[sub][t][3], C1, C2))) };
                *(uint2*)&Ps[64 * sub + 16 * w + l15][16 * t + 4 * quad] = pv;
            }
        // ---- O += P @ V; l += P @ 1 (register fragment, no LDS read) ----
        #pragma unroll
        for (int ks = 0; ks < 2; ++ks) {
            bf16x8 af0 = ldb8(&Ps[16 * w + l15][ks * 32 + quad * 8]);
            bf16x8 af1 = ldb8(&Ps[64 + 16 * w + l15][ks * 32 + quad * 8]);
            #pragma unroll
            for (int dt = 0; dt < 4; ++dt) {
                bf16x8 vf = ldb8(&Vt[16 * dt + l15][ks * 32 + quad * 8]);
                Od[0][dt] = mfma32(af0, vf, Od[0][dt]);
                Od[1][dt] = mfma32(af1, vf, Od[1][dt]);
            }
            Ol[0] = mfma32(af0, onesf, Ol[0]);
            Ol[1] = mfma32(af1, onesf, Ol[1]);
        }
    }

    // ---- epilogue ----
    u16* Ob = Opart + (size_t)s * 4096 * 512;
    #pragma unroll
    for (int sub = 0; sub < 2; ++sub) {
        #pragma unroll
        for (int r = 0; r < 4; ++r) {
            int row = ro + 64 * sub + 16 * w + quad * 4 + r;
            #pragma unroll
            for (int dt = 0; dt < 4; ++dt) {
                int col = h * 64 + 16 * dt + l15;
                Ob[(size_t)row * 512 + col] = f2bf(Od[sub][dt][r]);
            }
            if (l15 == 0)
                Lpart[((size_t)s * 4096 + row) * 8 + h] = Ol[sub][r];
        }
    }
}

// ---------------------------------------------------------------------------
// 4-dispatch pipeline: prep -> gemm1 -> attn -> gemm2(+fused merge).
// merge_kernel deleted (its math now in gemm2's FM A-staging, proven r4).
// ---------------------------------------------------------------------------
extern "C" void kernel_launch(void* const* d_in, const int* in_sizes, int n_in,
                              void* d_out, int out_size, void* d_ws, size_t ws_size,
                              hipStream_t stream)
{
    (void)in_sizes; (void)n_in; (void)out_size; (void)ws_size;
    const float* x   = (const float*)d_in[0];
    const float* wq  = (const float*)d_in[1];
    const float* wkv = (const float*)d_in[2];
    const float* wo  = (const float*)d_in[3];
    const float* bo  = (const float*)d_in[4];
    const float* mk  = (const float*)d_in[5];
    const float* mv  = (const float*)d_in[6];
    float* out = (float*)d_out;

    // non-aliased workspace layout (no address reuse across phases)
    u16* qkv    = (u16*)d_ws;                 // 6,488,064 u16
    u16* woT    = qkv + 6488064;              //   262,144
    u16* wqkvT  = woT + 262144;               //   786,432
    u16* xb     = wqkvT + 786432;             // 2,097,152
    u16* Opart  = xb + 2097152;               // 8,388,608 (4 slabs of 4096x512)
    float* Lpart = (float*)(Opart + 8388608); //   131,072 f32

    prep<<<2816, 256, 0, stream>>>(wq, wkv, wo, x, mk, mv, wqkvT, woT, xb, qkv);
    gemmK<128, 64, false, false><<<dim3(32, 24), 256, 0, stream>>>(
        xb, 512, wqkvT, 512, qkv, 1536, nullptr, 512, 64, nullptr, nullptr);
    attn_kernel<<<dim3(64, 8, 2), 256, 0, stream>>>(qkv, Opart, Lpart);
    gemmK<64, 64, true, true><<<dim3(64, 8), 256, 0, stream>>>(
        nullptr, 512, woT, 512, out, 512, bo, 512, 0, Opart, Lpart);
}